// Round 12
// baseline (1295.970 us; speedup 1.0000x reference)
//
#include <hip/hip_runtime.h>
#include <hip/hip_fp16.h>
#include <cstddef>
#include <cstdint>

// QuantizedThriftyNet on MI355X — round 11.
// R10 = best (1031us). Conv S=64 pinned ~135us across 5 schedule variants;
// this round harvests safe wins instead:
//  * dispatch fusion: stats_final -> bn_apply_fused / pool3 (in-kernel LDS
//    reduce of psum), wmax_final -> quant, amax+linear -> head. 67 -> 45
//    dispatches (~3us each).
//  * XCD co-location remap in all convs: the 4 co-group blocks sharing an
//    X tile become dispatch-adjacent mod 8 -> same XCD L2 -> X crosses the
//    L2-miss path once instead of 4x (pure block permutation).
// Conv MFMA accumulation order bit-identical to R4-R10.

#define NB 16
#define NIT 20

typedef _Float16 half8 __attribute__((ext_vector_type(8)));
typedef _Float16 half4v __attribute__((ext_vector_type(4)));
typedef float floatx4 __attribute__((ext_vector_type(4)));

__device__ __forceinline__ void gl_lds16(const void* g, void* l) {
  __builtin_amdgcn_global_load_lds(
      (const __attribute__((address_space(1))) unsigned int*)g,
      (__attribute__((address_space(3))) unsigned int*)l, 16, 0, 0);
}

template <int N>
__device__ __forceinline__ void wait_vm() {
  if constexpr (N == 0) asm volatile("s_waitcnt vmcnt(0)" ::: "memory");
  else if constexpr (N == 5) asm volatile("s_waitcnt vmcnt(5)" ::: "memory");
  else if constexpr (N == 6) asm volatile("s_waitcnt vmcnt(6)" ::: "memory");
  else static_assert(N == 0 || N == 5 || N == 6, "add vmcnt literal");
}

// XCD co-location: consecutive-8 dispatch ids = 8 tiles on XCD 0..7; the 4
// co-groups of one tile are 8 apart -> same XCD. Requires ntile%8==0.
__device__ __forceinline__ void xcd_remap(int ntile, int& tile, int& cog) {
  int lin = blockIdx.y * gridDim.x + blockIdx.x;
  cog = (lin >> 3) & 3;
  tile = (lin & 7) + ((lin >> 5) << 3);
  (void)ntile;
}

// ---------------- weight max partials ---------------------------------------
__global__ void wmax_part_kernel(const float* __restrict__ w, float* __restrict__ part, int n) {
  float m = 0.f;
  for (int i = blockIdx.x * blockDim.x + threadIdx.x; i < n; i += gridDim.x * blockDim.x)
    m = fmaxf(m, fabsf(w[i]));
  #pragma unroll
  for (int o = 32; o > 0; o >>= 1) m = fmaxf(m, __shfl_down(m, o));
  __shared__ float sm[4];
  int wid = threadIdx.x >> 6, lane = threadIdx.x & 63;
  if (lane == 0) sm[wid] = m;
  __syncthreads();
  if (threadIdx.x == 0) part[blockIdx.x] = fmaxf(fmaxf(sm[0], sm[1]), fmaxf(sm[2], sm[3]));
}

// quantize + repack (fused final wmax reduce of the 256 partials per block)
__global__ void quant_kernel(const float* __restrict__ w, const float* __restrict__ part,
                             _Float16* __restrict__ wqr, int nw) {
  __shared__ float sm[4];
  __shared__ float sS;
  float m = part[threadIdx.x];  // 256 partials, 256 threads
  #pragma unroll
  for (int o = 32; o > 0; o >>= 1) m = fmaxf(m, __shfl_down(m, o));
  int wid = threadIdx.x >> 6, lane = threadIdx.x & 63;
  if (lane == 0) sm[wid] = m;
  __syncthreads();
  if (threadIdx.x == 0) sS = fmaxf(fmaxf(sm[0], sm[1]), fmaxf(sm[2], sm[3])) / 127.f;
  __syncthreads();
  float s = sS;
  int d = blockIdx.x * 256 + threadIdx.x;
  if (d >= nw) return;
  int frag = d >> 9;
  int e = d & 511;
  int l = e >> 3, j = e & 7;
  int tap = frag >> 7;
  int rem = frag & 127;
  int cog = rem >> 3, chk = rem & 7;
  int co = cog * 16 + (l & 15);
  int ci = chk * 32 + (l >> 4) * 8 + j;
  float q = rintf(w[((size_t)co * 256 + ci) * 9 + tap] / s) * s;  // round-half-even
  wqr[d] = (_Float16)q;
}

// ---------------- pad x fp32 NCHW -> f16 NHWC --------------------------------
__global__ void pad_kernel(const float* __restrict__ x, _Float16* __restrict__ out) {
  int idx = blockIdx.x * 256 + threadIdx.x;
  int c = idx & 255;
  int pos = idx >> 8;
  int hw = pos & 4095;
  int n = pos >> 12;
  float v = 0.f;
  if (c < 3) v = x[(n * 3 + c) * 4096 + hw];
  out[idx] = (_Float16)v;
}

// ---------------- conv v7: counted-vmcnt pipeline (nc chunks) ----------------
// Block: 64 co x 512 pix, 8 waves, wave tile 64co x 64pix. K = nc chunks x 9.
template <int S, int R>
__global__ __launch_bounds__(512, 2) void conv_mfma_v7(
    const _Float16* __restrict__ in, const _Float16* __restrict__ wqr,
    const float* __restrict__ alpha, int t, int nc,
    const _Float16* h1, const _Float16* __restrict__ h2,
    const _Float16* __restrict__ h3, _Float16* pre,
    const _Float16* __restrict__ zpage,
    float* __restrict__ psum, float* __restrict__ psum2) {
  constexpr int NT = 512;
  constexpr int LW = S + 2;
  constexpr int XSLOT = (R + 2) * LW * 4;
  constexpr int XI = (XSLOT + NT - 1) / NT;
  constexpr int XPAD = XI * NT;
  constexpr int WSLOT = 36 * 64;
  constexpr int WI = (WSLOT + NT - 1) / NT;
  constexpr int WPAD = WI * NT;
  static_assert(R * S == 512, "block pixel tile must be 512");

  __shared__ half8 xl[2][XPAD];
  __shared__ half8 wl[WPAD];

  const int tid = threadIdx.x;
  const int lane = tid & 63;
  const int wid = tid >> 6;
  const int l16 = lane & 15;
  const int kg = lane >> 4;
  const int wn = wid;

  constexpr int BPI = S / R;
  int tile, cog;
  xcd_remap(NB * BPI, tile, cog);
  const int n = tile / BPI;
  const int rb = tile % BPI;
  const int cob = cog * 64;

  const _Float16* img = in + (size_t)n * S * S * 256;

  int rg[4], cg[4];
  #pragma unroll
  for (int g = 0; g < 4; ++g) {
    int lp = wn * 64 + g * 16 + l16;
    rg[g] = lp / S;
    cg[g] = lp - rg[g] * S;
  }

  floatx4 acc[4][4];
  #pragma unroll
  for (int f = 0; f < 4; ++f)
    #pragma unroll
    for (int g = 0; g < 4; ++g)
      acc[f][g] = (floatx4){0.f, 0.f, 0.f, 0.f};

  auto stageX = [&](int buf, int c) {
    const _Float16* cbase = img + c * 32;
    #pragma unroll
    for (int i = 0; i < XI; ++i) {
      int slot = i * NT + tid;
      const void* g = (const void*)zpage;
      if (slot < XSLOT) {
        int pix = slot >> 2;
        int cig = (slot & 3) ^ ((pix >> 1) & 3);
        int hp = pix / LW, wp = pix - hp * LW;
        int h = rb * R + hp - 1, w = wp - 1;
        if ((unsigned)h < (unsigned)S && (unsigned)w < (unsigned)S)
          g = (const void*)(cbase + (size_t)(h * S + w) * 256 + cig * 8);
      }
      gl_lds16(g, (void*)&xl[buf][slot]);
    }
  };

  auto stageW = [&](int c) {
    #pragma unroll
    for (int i = 0; i < WI; ++i) {
      int slot = i * NT + tid;
      const void* g = (const void*)zpage;
      if (slot < WSLOT) {
        int fb = slot >> 6;
        int tap = fb >> 2, f = fb & 3;
        int ll = slot & 63;
        g = (const void*)(wqr +
            ((((size_t)tap * 16 + cog * 4 + f) * 8 + c) << 9) + ll * 8);
      }
      gl_lds16(g, (void*)&wl[slot]);
    }
  };

  auto compute = [&](const half8* xb) {
    #pragma unroll
    for (int tap = 0; tap < 9; ++tap) {
      const int dh = tap / 3 - 1;
      const int dw = tap - (tap / 3) * 3 - 1;
      half8 af[4];
      #pragma unroll
      for (int f = 0; f < 4; ++f)
        af[f] = wl[(tap * 4 + f) * 64 + lane];
      half8 bf[4];
      #pragma unroll
      for (int g = 0; g < 4; ++g) {
        int xp = (rg[g] + 1 + dh) * LW + (cg[g] + 1 + dw);
        bf[g] = xb[xp * 4 + (kg ^ ((xp >> 1) & 3))];
      }
      #pragma unroll
      for (int f = 0; f < 4; ++f)
        #pragma unroll
        for (int g = 0; g < 4; ++g)
          acc[f][g] = __builtin_amdgcn_mfma_f32_16x16x32_f16(af[f], bf[g], acc[f][g], 0, 0, 0);
    }
  };

  stageX(0, 0);
  stageW(0);
  wait_vm<0>();
  __builtin_amdgcn_sched_barrier(0);
  __builtin_amdgcn_s_barrier();
  __builtin_amdgcn_sched_barrier(0);

  for (int c = 0; c < nc; ++c) {
    if (c + 1 < nc) stageX((c + 1) & 1, c + 1);
    if (c > 0) {
      if (c + 1 < nc) wait_vm<XI>();
      else wait_vm<0>();
      __builtin_amdgcn_sched_barrier(0);
      __builtin_amdgcn_s_barrier();
      __builtin_amdgcn_sched_barrier(0);
    }
    compute(&xl[c & 1][0]);
    __builtin_amdgcn_sched_barrier(0);
    __builtin_amdgcn_s_barrier();
    __builtin_amdgcn_sched_barrier(0);
    if (c + 1 < nc) stageW(c + 1);
  }

  // ---- epilogue: combine + write + fused BN partials ----
  const float a0 = alpha[t * 5 + 0];
  const float a1 = alpha[t * 5 + 2];
  const float a2 = alpha[t * 5 + 3];
  const float a3 = alpha[t * 5 + 4];
  float cs[4][4], cq[4][4];
  #pragma unroll
  for (int f = 0; f < 4; ++f)
    #pragma unroll
    for (int r = 0; r < 4; ++r) { cs[f][r] = 0.f; cq[f][r] = 0.f; }

  const size_t pixbase = (size_t)n * S * S + (size_t)rb * (R * S);
  #pragma unroll
  for (int f = 0; f < 4; ++f) {
    const int co = cob + f * 16 + kg * 4;
    #pragma unroll
    for (int g = 0; g < 4; ++g) {
      int lp = wn * 64 + g * 16 + l16;
      size_t idx = (pixbase + lp) * 256 + co;
      half4v v3 = *(const half4v*)(h3 + idx);
      half4v v1 = {}, v2 = {};
      if (h1) v1 = *(const half4v*)(h1 + idx);
      if (h2) v2 = *(const half4v*)(h2 + idx);
      half4v o;
      #pragma unroll
      for (int r = 0; r < 4; ++r) {
        float pv = a0 * fmaxf(acc[f][g][r], 0.f) + a3 * (float)v3[r];
        if (h1) pv += a1 * (float)v1[r];
        if (h2) pv += a2 * (float)v2[r];
        o[r] = (_Float16)pv;
        cs[f][r] += pv;
        cq[f][r] += pv * pv;
      }
      *(half4v*)(pre + idx) = o;  // pre may alias h1: same-thread RaW, safe
    }
  }

  float* sred = reinterpret_cast<float*>(&wl[0]);  // 512 ss + 512 sq floats
  #pragma unroll
  for (int f = 0; f < 4; ++f)
    #pragma unroll
    for (int r = 0; r < 4; ++r) {
      float a = cs[f][r], b = cq[f][r];
      #pragma unroll
      for (int m = 1; m < 16; m <<= 1) {
        a += __shfl_xor(a, m);
        b += __shfl_xor(b, m);
      }
      if (l16 == 0) {
        sred[wn * 64 + f * 16 + kg * 4 + r] = a;
        sred[512 + wn * 64 + f * 16 + kg * 4 + r] = b;
      }
    }
  __syncthreads();
  if (tid < 64) {
    float a = 0.f, b = 0.f;
    #pragma unroll
    for (int w = 0; w < 8; ++w) {
      a += sred[w * 64 + tid];
      b += sred[512 + w * 64 + tid];
    }
    psum[(size_t)tile * 256 + cob + tid] = a;
    psum2[(size_t)tile * 256 + cob + tid] = b;
  }
}

// ---------------- round-3 kernel for S=32/16/8 -------------------------------
template <int S, int R>
__global__ __launch_bounds__(512, 2) void conv_mfma_sm(
    const _Float16* __restrict__ in, const _Float16* __restrict__ wqr,
    const float* __restrict__ alpha, int t,
    const _Float16* h1, const _Float16* __restrict__ h2,
    const _Float16* __restrict__ h3, _Float16* pre,
    const _Float16* __restrict__ zpage,
    float* __restrict__ psum, float* __restrict__ psum2) {
  constexpr int LW = S + 2;
  constexpr int PIX = (R + 2) * LW;
  constexpr int XS = PIX * 4;
  constexpr int XS_PAD = ((XS + 63) / 64) * 64;
  constexpr int WS = 36 * 64;
  constexpr int PIXB = R * S;
  constexpr int G = PIXB / 64;

  __shared__ half8 xl[2][XS_PAD];
  __shared__ half8 wl[2][WS];
  __shared__ float sred[8][4][2][4];
  __shared__ float sredq[8][4][2][4];

  const int tid = threadIdx.x;
  const int lane = tid & 63;
  const int wid = tid >> 6;
  const int l16 = lane & 15;
  const int kg = lane >> 4;
  const int wm = wid >> 2;
  const int wn = wid & 3;

  constexpr int BPI = S / R;
  int tile, cog;
  xcd_remap(NB * BPI, tile, cog);
  const int n = tile / BPI;
  const int rb = tile % BPI;
  const int cob = cog * 64;

  const _Float16* img = in + (size_t)n * S * S * 256;

  floatx4 acc[2][G];
  #pragma unroll
  for (int f = 0; f < 2; ++f)
    #pragma unroll
    for (int g = 0; g < G; ++g)
      acc[f][g] = (floatx4){0.f, 0.f, 0.f, 0.f};

  auto stage = [&](int buf, int c) {
    const _Float16* cbase = img + c * 32;
    for (int sb = wid * 64; sb < XS_PAD; sb += 512) {
      int slot = sb + lane;
      const void* g = (const void*)zpage;
      if (slot < XS) {
        int pix = slot >> 2;
        int cig = (slot & 3) ^ ((pix >> 1) & 3);
        int hp = pix / LW, wp = pix - hp * LW;
        int h = rb * R + hp - 1, w = wp - 1;
        if ((unsigned)h < (unsigned)S && (unsigned)w < (unsigned)S)
          g = (const void*)(cbase + (size_t)(h * S + w) * 256 + cig * 8);
      }
      gl_lds16(g, (void*)&xl[buf][sb]);
    }
    for (int fb = wid; fb < 36; fb += 8) {
      int tap = fb >> 2, cogl = fb & 3;
      const _Float16* g = wqr +
          ((((size_t)tap * 16 + cog * 4 + cogl) * 8 + c) << 9) + lane * 8;
      gl_lds16((const void*)g, (void*)&wl[buf][fb * 64]);
    }
  };

  auto compute = [&](int buf) {
    #pragma unroll
    for (int dh = -1; dh <= 1; ++dh) {
      #pragma unroll
      for (int dw = -1; dw <= 1; ++dw) {
        const int tap = (dh + 1) * 3 + (dw + 1);
        half8 af[2];
        #pragma unroll
        for (int f = 0; f < 2; ++f)
          af[f] = wl[buf][(tap * 4 + wm * 2 + f) * 64 + lane];
        half8 bf[G];
        #pragma unroll
        for (int g = 0; g < G; ++g) {
          int p = wn * (PIXB / 4) + g * 16 + l16;
          int r = p / S, cc = p - r * S;
          int lp = (r + 1 + dh) * LW + (cc + 1 + dw);
          bf[g] = xl[buf][lp * 4 + (kg ^ ((lp >> 1) & 3))];
        }
        #pragma unroll
        for (int f = 0; f < 2; ++f)
          #pragma unroll
          for (int g = 0; g < G; ++g)
            acc[f][g] = __builtin_amdgcn_mfma_f32_16x16x32_f16(af[f], bf[g], acc[f][g], 0, 0, 0);
      }
    }
  };

  stage(0, 0);
  __syncthreads();
  for (int c = 0; c < 8; ++c) {
    if (c < 7) stage((c + 1) & 1, c + 1);
    compute(c & 1);
    __syncthreads();
  }

  const float a0 = alpha[t * 5 + 0];
  const float a1 = alpha[t * 5 + 2];
  const float a2 = alpha[t * 5 + 3];
  const float a3 = alpha[t * 5 + 4];
  float ss[2][4], sq[2][4];
  #pragma unroll
  for (int f = 0; f < 2; ++f)
    #pragma unroll
    for (int r = 0; r < 4; ++r) { ss[f][r] = 0.f; sq[f][r] = 0.f; }

  const size_t pix0 = (size_t)n * S * S + (size_t)rb * PIXB;
  #pragma unroll
  for (int f = 0; f < 2; ++f) {
    const int co = cob + wm * 32 + f * 16 + kg * 4;
    #pragma unroll
    for (int g = 0; g < G; ++g) {
      int p = wn * (PIXB / 4) + g * 16 + l16;
      size_t idx = (pix0 + p) * 256 + co;
      half4v v3 = *(const half4v*)(h3 + idx);
      half4v v1 = {}, v2 = {};
      if (h1) v1 = *(const half4v*)(h1 + idx);
      if (h2) v2 = *(const half4v*)(h2 + idx);
      half4v o;
      #pragma unroll
      for (int r = 0; r < 4; ++r) {
        float pv = a0 * fmaxf(acc[f][g][r], 0.f) + a3 * (float)v3[r];
        if (h1) pv += a1 * (float)v1[r];
        if (h2) pv += a2 * (float)v2[r];
        o[r] = (_Float16)pv;
        ss[f][r] += pv;
        sq[f][r] += pv * pv;
      }
      *(half4v*)(pre + idx) = o;
    }
  }

  #pragma unroll
  for (int f = 0; f < 2; ++f)
    #pragma unroll
    for (int r = 0; r < 4; ++r) {
      float a = ss[f][r], b = sq[f][r];
      #pragma unroll
      for (int m = 1; m < 16; m <<= 1) {
        a += __shfl_xor(a, m);
        b += __shfl_xor(b, m);
      }
      if (l16 == 0) { sred[wid][kg][f][r] = a; sredq[wid][kg][f][r] = b; }
    }
  __syncthreads();
  if (tid < 64) {
    int ch = tid;
    int wmm = ch >> 5, ff = (ch >> 4) & 1, kk = (ch >> 2) & 3, rr = ch & 3;
    float a = 0.f, b = 0.f;
    #pragma unroll
    for (int w = 0; w < 4; ++w) {
      a += sred[wmm * 4 + w][kk][ff][rr];
      b += sredq[wmm * 4 + w][kk][ff][rr];
    }
    psum[(size_t)tile * 256 + cob + ch] = a;
    psum2[(size_t)tile * 256 + cob + ch] = b;
  }
}

// ---------------- fused BN stats + apply (non-pool iters) ---------------------
// Each block redundantly reduces psum/psum2 -> scale/shift in LDS (serial
// over nblk, deterministic), then grid-strides the elementwise apply.
__global__ __launch_bounds__(256) void bn_apply_fused(
    _Float16* __restrict__ x, const float* __restrict__ psum,
    const float* __restrict__ psum2, const float* __restrict__ gamma,
    const float* __restrict__ beta, int t, float M, int nblk, int n8) {
  __shared__ float ssc[256], ssh[256];
  {
    int c = threadIdx.x;
    float s = 0.f, s2 = 0.f;
    for (int b = 0; b < nblk; ++b) {
      s += psum[(size_t)b * 256 + c];
      s2 += psum2[(size_t)b * 256 + c];
    }
    float mean = s / M;
    float var = s2 / M - mean * mean;  // biased, matches jnp.var
    float sc = gamma[t * 256 + c] * rsqrtf(var + 1e-5f);
    ssc[c] = sc;
    ssh[c] = beta[t * 256 + c] - mean * sc;
  }
  __syncthreads();
  for (int i = blockIdx.x * 256 + threadIdx.x; i < n8; i += gridDim.x * 256) {
    half8 v = *(half8*)(x + (size_t)i * 8);
    int c0 = (i * 8) & 255;
    half8 o;
    #pragma unroll
    for (int j = 0; j < 8; ++j) o[j] = (_Float16)((float)v[j] * ssc[c0 + j] + ssh[c0 + j]);
    *(half8*)(x + (size_t)i * 8) = o;
  }
}

// ---------------- fused pool (3 tensors) + BN stats+apply on z==2 -------------
__global__ __launch_bounds__(256) void pool3_kernel(
    const _Float16* __restrict__ s0, const _Float16* __restrict__ s1,
    const _Float16* __restrict__ s2,
    _Float16* __restrict__ d0, _Float16* __restrict__ d1, _Float16* __restrict__ d2,
    const float* __restrict__ psum, const float* __restrict__ psum2,
    const float* __restrict__ gamma, const float* __restrict__ beta,
    int t, float M, int nblk, int So, int total8) {
  __shared__ float ssc[256], ssh[256];
  int z = blockIdx.y;
  if (z == 2) {
    int c = threadIdx.x;
    float s = 0.f, s2 = 0.f;
    for (int b = 0; b < nblk; ++b) {
      s += psum[(size_t)b * 256 + c];
      s2 += psum2[(size_t)b * 256 + c];
    }
    float mean = s / M;
    float var = s2 / M - mean * mean;
    float sc = gamma[t * 256 + c] * rsqrtf(var + 1e-5f);
    ssc[c] = sc;
    ssh[c] = beta[t * 256 + c] - mean * sc;
    __syncthreads();
  }
  const _Float16* in = (z == 0) ? s0 : (z == 1) ? s1 : s2;
  _Float16* out = (z == 0) ? d0 : (z == 1) ? d1 : d2;
  int Si = So * 2;
  for (int i = blockIdx.x * 256 + threadIdx.x; i < total8; i += gridDim.x * 256) {
    int c0 = (i & 31) * 8;
    int pix = i >> 5;
    int wo = pix % So;
    int t1 = pix / So;
    int ho = t1 % So;
    int n = t1 / So;
    size_t b00 = ((size_t)(n * Si * Si) + (2 * ho) * Si + 2 * wo) * 256 + c0;
    half8 v00 = *(const half8*)(in + b00);
    half8 v01 = *(const half8*)(in + b00 + 256);
    half8 v10 = *(const half8*)(in + b00 + (size_t)Si * 256);
    half8 v11 = *(const half8*)(in + b00 + (size_t)Si * 256 + 256);
    half8 o;
    if (z == 2) {
      #pragma unroll
      for (int j = 0; j < 8; ++j) {
        float sc = ssc[c0 + j], sh = ssh[c0 + j];
        float a = (float)v00[j] * sc + sh;
        float b = (float)v01[j] * sc + sh;
        float c = (float)v10[j] * sc + sh;
        float d = (float)v11[j] * sc + sh;
        o[j] = (_Float16)fmaxf(fmaxf(a, b), fmaxf(c, d));
      }
    } else {
      #pragma unroll
      for (int j = 0; j < 8; ++j) {
        float m = fmaxf(fmaxf((float)v00[j], (float)v01[j]),
                        fmaxf((float)v10[j], (float)v11[j]));
        o[j] = (_Float16)m;
      }
    }
    *(half8*)(out + (size_t)pix * 256 + c0) = o;
  }
}

// ---------------- fused head: spatial max (S=4) + linear ----------------------
__global__ __launch_bounds__(256) void head_kernel(
    const _Float16* __restrict__ x, const float* __restrict__ W,
    const float* __restrict__ b, float* __restrict__ out) {
  __shared__ float v[256];
  int n = blockIdx.x, c = threadIdx.x;
  float m = -1e30f;
  for (int p = 0; p < 16; ++p)
    m = fmaxf(m, (float)x[((size_t)(n * 16 + p)) * 256 + c]);
  v[c] = m;
  __syncthreads();
  if (c < 100) {
    float s = b[c];
    const float* w = W + c * 256;
    for (int k = 0; k < 256; ++k) s += v[k] * w[k];
    out[n * 100 + c] = s;
  }
}

// -------------------------------------------------------------------------------
extern "C" void kernel_launch(void* const* d_in, const int* in_sizes, int n_in,
                              void* d_out, int out_size, void* d_ws, size_t ws_size,
                              hipStream_t stream) {
  const float* x        = (const float*)d_in[0];
  const float* conv_w   = (const float*)d_in[1];
  const float* alpha    = (const float*)d_in[2];
  const float* bn_gamma = (const float*)d_in[3];
  const float* bn_beta  = (const float*)d_in[4];
  const float* out_w    = (const float*)d_in[5];
  const float* out_b    = (const float*)d_in[6];
  float* out = (float*)d_out;

  char* ws = (char*)d_ws;
  size_t off = 0;
  auto alloc = [&](size_t bytes) -> void* {
    void* p = (void*)(ws + off);
    off = (off + bytes + 255) & ~(size_t)255;
    return p;
  };
  const size_t SLAB = (size_t)NB * 4096 * 256 * 2;  // 32 MiB
  char* slab[4];
  size_t slabsz[4];
  for (int i = 0; i < 3; ++i) { slab[i] = (char*)alloc(SLAB); slabsz[i] = SLAB; }
  slab[3] = (char*)alloc(3 * (SLAB / 4)); slabsz[3] = 3 * (SLAB / 4);  // 24 MiB
  _Float16* wqr  = (_Float16*)alloc((size_t)9 * 256 * 256 * 2);
  float* wpart = (float*)alloc(256 * 4);
  float* psum  = (float*)alloc(256 * 256 * 4);
  float* psum2 = (float*)alloc(256 * 256 * 4);
  _Float16* zpage = (_Float16*)alloc(256);
  (void)ws_size;  // ~123 MiB

  const int NW = 256 * 256 * 9;

  hipMemsetAsync(zpage, 0, 256, stream);

  hipLaunchKernelGGL(wmax_part_kernel, dim3(256), dim3(256), 0, stream, conv_w, wpart, NW);
  hipLaunchKernelGGL(quant_kernel, dim3((NW + 255) / 256), dim3(256), 0, stream,
                     conv_w, wpart, wqr, NW);

  hipLaunchKernelGGL(pad_kernel, dim3((NB * 4096 * 256) / 256), dim3(256), 0, stream,
                     x, (_Float16*)slab[0]);

  auto contains = [&](int k, char* p) -> bool {
    return p && p >= slab[k] && p < slab[k] + slabsz[k];
  };

  char *p1 = nullptr, *p2 = nullptr, *p3 = slab[0];
  int S = 64;
  for (int t = 0; t < NIT; ++t) {
    char* dst;
    if (p1) {
      dst = p1;  // overwrite dying hist[1] in place
    } else {
      dst = nullptr;
      for (int k = 0; k < 3; ++k)
        if (!contains(k, p2) && !contains(k, p3)) { dst = slab[k]; break; }
    }
    const _Float16* h1 = (const _Float16*)p1;
    const _Float16* h2 = (const _Float16*)p2;
    const _Float16* h3 = (const _Float16*)p3;
    _Float16* pre = (_Float16*)dst;

    int nblk;
    switch (S) {
      case 64: {  // 64co x 512pix, 8 waves, counted-vmcnt pipeline
        int nc = (t == 0) ? 1 : 8;  // t=0: channels 3..255 exactly zero
        dim3 grid(NB * 8, 4);  nblk = NB * 8;
        hipLaunchKernelGGL((conv_mfma_v7<64, 8>), grid, dim3(512), 0, stream,
                           h3, wqr, alpha, t, nc, h1, h2, h3, pre, zpage, psum, psum2);
        break;
      }
      case 32: {  // 256 blocks = full GPU
        dim3 grid(NB * 4, 4);  nblk = NB * 4;
        hipLaunchKernelGGL((conv_mfma_sm<32, 8>), grid, dim3(512), 0, stream,
                           h3, wqr, alpha, t, h1, h2, h3, pre, zpage, psum, psum2);
        break;
      }
      case 16: {
        dim3 grid(NB * 4, 4);  nblk = NB * 4;
        hipLaunchKernelGGL((conv_mfma_sm<16, 4>), grid, dim3(512), 0, stream,
                           h3, wqr, alpha, t, h1, h2, h3, pre, zpage, psum, psum2);
        break;
      }
      default: {
        dim3 grid(NB * 1, 4);  nblk = NB * 1;
        hipLaunchKernelGGL((conv_mfma_sm<8, 8>), grid, dim3(512), 0, stream,
                           h3, wqr, alpha, t, h1, h2, h3, pre, zpage, psum, psum2);
        break;
      }
    }

    int npix = NB * S * S;

    if (t % 5 != 4) {
      int n8 = npix * 32;
      int blocks = (n8 + 255) / 256;
      if (blocks > 512) blocks = 512;
      hipLaunchKernelGGL(bn_apply_fused, dim3(blocks), dim3(256), 0, stream,
                         pre, psum, psum2, bn_gamma, bn_beta, t, (float)npix, nblk, n8);
      p1 = p2; p2 = p3; p3 = dst;
    } else {
      char* q1 = p2;
      char* q2 = p3;
      char* q3 = dst;
      int So = S / 2;
      size_t qbytes = (size_t)NB * So * So * 256 * 2;
      char* fs = nullptr;
      for (int k = 0; k < 4; ++k)
        if (!contains(k, q1) && !contains(k, q2) && !contains(k, q3)) { fs = slab[k]; break; }
      int total8 = NB * So * So * 32;
      int pgx = (total8 + 255) / 256;
      if (pgx > 512) pgx = 512;
      dim3 pg(pgx, 3);
      hipLaunchKernelGGL(pool3_kernel, pg, dim3(256), 0, stream,
                         (const _Float16*)q1, (const _Float16*)q2, (const _Float16*)q3,
                         (_Float16*)fs, (_Float16*)(fs + qbytes), (_Float16*)(fs + 2 * qbytes),
                         psum, psum2, bn_gamma, bn_beta, t, (float)npix, nblk, So, total8);
      p1 = fs; p2 = fs + qbytes; p3 = fs + 2 * qbytes;
      S = So;
    }
  }

  hipLaunchKernelGGL(head_kernel, dim3(16), dim3(256), 0, stream,
                     (const _Float16*)p3, out_w, out_b, out);
}

// Round 13
// 1026.373 us; speedup vs baseline: 1.2627x; 1.2627x over previous
//
#include <hip/hip_runtime.h>
#include <hip/hip_fp16.h>
#include <cstddef>
#include <cstdint>

// QuantizedThriftyNet on MI355X — round 12 (consolidation).
// R11 post-mortem: fused per-block serial BN reduce cost ~14us x 20 dispatches
// (-265us); XCD remap neutral. Reverted to R10 (best, 1031us) keeping only:
//  * wmax_final fused into quant (runs once)
//  * amax+linear fused into head (runs once)
//  * apply_kernel grid-stride capped at 2048 blocks (was 8192)
// Conv accumulation order bit-identical to R4-R11.

#define NB 16
#define NIT 20

typedef _Float16 half8 __attribute__((ext_vector_type(8)));
typedef _Float16 half4v __attribute__((ext_vector_type(4)));
typedef float floatx4 __attribute__((ext_vector_type(4)));

__device__ __forceinline__ void gl_lds16(const void* g, void* l) {
  __builtin_amdgcn_global_load_lds(
      (const __attribute__((address_space(1))) unsigned int*)g,
      (__attribute__((address_space(3))) unsigned int*)l, 16, 0, 0);
}

template <int N>
__device__ __forceinline__ void wait_vm() {
  if constexpr (N == 0) asm volatile("s_waitcnt vmcnt(0)" ::: "memory");
  else if constexpr (N == 5) asm volatile("s_waitcnt vmcnt(5)" ::: "memory");
  else if constexpr (N == 6) asm volatile("s_waitcnt vmcnt(6)" ::: "memory");
  else static_assert(N == 0 || N == 5 || N == 6, "add vmcnt literal");
}

// ---------------- weight max partials ---------------------------------------
__global__ void wmax_part_kernel(const float* __restrict__ w, float* __restrict__ part, int n) {
  float m = 0.f;
  for (int i = blockIdx.x * blockDim.x + threadIdx.x; i < n; i += gridDim.x * blockDim.x)
    m = fmaxf(m, fabsf(w[i]));
  #pragma unroll
  for (int o = 32; o > 0; o >>= 1) m = fmaxf(m, __shfl_down(m, o));
  __shared__ float sm[4];
  int wid = threadIdx.x >> 6, lane = threadIdx.x & 63;
  if (lane == 0) sm[wid] = m;
  __syncthreads();
  if (threadIdx.x == 0) part[blockIdx.x] = fmaxf(fmaxf(sm[0], sm[1]), fmaxf(sm[2], sm[3]));
}

// quantize + repack (wmax final reduce fused; runs once, 256 partials/block)
__global__ void quant_kernel(const float* __restrict__ w, const float* __restrict__ part,
                             _Float16* __restrict__ wqr, int nw) {
  __shared__ float sm[4];
  __shared__ float sS;
  float m = part[threadIdx.x];
  #pragma unroll
  for (int o = 32; o > 0; o >>= 1) m = fmaxf(m, __shfl_down(m, o));
  int wid = threadIdx.x >> 6, lane = threadIdx.x & 63;
  if (lane == 0) sm[wid] = m;
  __syncthreads();
  if (threadIdx.x == 0) sS = fmaxf(fmaxf(sm[0], sm[1]), fmaxf(sm[2], sm[3])) / 127.f;
  __syncthreads();
  float s = sS;
  int d = blockIdx.x * 256 + threadIdx.x;
  if (d >= nw) return;
  int frag = d >> 9;
  int e = d & 511;
  int l = e >> 3, j = e & 7;
  int tap = frag >> 7;
  int rem = frag & 127;
  int cog = rem >> 3, chk = rem & 7;
  int co = cog * 16 + (l & 15);
  int ci = chk * 32 + (l >> 4) * 8 + j;
  float q = rintf(w[((size_t)co * 256 + ci) * 9 + tap] / s) * s;  // round-half-even
  wqr[d] = (_Float16)q;
}

// ---------------- pad x fp32 NCHW -> f16 NHWC --------------------------------
__global__ void pad_kernel(const float* __restrict__ x, _Float16* __restrict__ out) {
  int idx = blockIdx.x * 256 + threadIdx.x;
  int c = idx & 255;
  int pos = idx >> 8;
  int hw = pos & 4095;
  int n = pos >> 12;
  float v = 0.f;
  if (c < 3) v = x[(n * 3 + c) * 4096 + hw];
  out[idx] = (_Float16)v;
}

// ---------------- conv v7: counted-vmcnt pipeline (nc chunks) ----------------
// Block: 64 co x 512 pix (R*S==512), 8 waves, wave tile 64co x 64pix.
// K = nc chunks x 9 taps (nc==1 for the sparse t=0 conv, else 8).
template <int S, int R>
__global__ __launch_bounds__(512, 2) void conv_mfma_v7(
    const _Float16* __restrict__ in, const _Float16* __restrict__ wqr,
    const float* __restrict__ alpha, int t, int nc,
    const _Float16* h1, const _Float16* __restrict__ h2,
    const _Float16* __restrict__ h3, _Float16* pre,
    const _Float16* __restrict__ zpage,
    float* __restrict__ psum, float* __restrict__ psum2) {
  constexpr int NT = 512;
  constexpr int LW = S + 2;
  constexpr int XSLOT = (R + 2) * LW * 4;        // real 16B slots per X buffer
  constexpr int XI = (XSLOT + NT - 1) / NT;      // gl_lds issues per thread
  constexpr int XPAD = XI * NT;
  constexpr int WSLOT = 36 * 64;                 // 9 taps * 4 frags * 64 = 2304
  constexpr int WI = (WSLOT + NT - 1) / NT;      // 5
  constexpr int WPAD = WI * NT;                  // 2560
  static_assert(R * S == 512, "block pixel tile must be 512");

  __shared__ half8 xl[2][XPAD];
  __shared__ half8 wl[WPAD];

  const int tid = threadIdx.x;
  const int lane = tid & 63;
  const int wid = tid >> 6;
  const int l16 = lane & 15;
  const int kg = lane >> 4;
  const int wn = wid;                            // pixel sub-block (0..7)

  constexpr int BPI = S / R;
  const int n = blockIdx.x / BPI;
  const int rb = blockIdx.x % BPI;
  const int cob = blockIdx.y * 64;

  const _Float16* img = in + (size_t)n * S * S * 256;

  int rg[4], cg[4];
  #pragma unroll
  for (int g = 0; g < 4; ++g) {
    int lp = wn * 64 + g * 16 + l16;
    rg[g] = lp / S;
    cg[g] = lp - rg[g] * S;
  }

  floatx4 acc[4][4];
  #pragma unroll
  for (int f = 0; f < 4; ++f)
    #pragma unroll
    for (int g = 0; g < 4; ++g)
      acc[f][g] = (floatx4){0.f, 0.f, 0.f, 0.f};

  auto stageX = [&](int buf, int c) {
    const _Float16* cbase = img + c * 32;
    #pragma unroll
    for (int i = 0; i < XI; ++i) {
      int slot = i * NT + tid;
      const void* g = (const void*)zpage;
      if (slot < XSLOT) {
        int pix = slot >> 2;
        int cig = (slot & 3) ^ ((pix >> 1) & 3);
        int hp = pix / LW, wp = pix - hp * LW;
        int h = rb * R + hp - 1, w = wp - 1;
        if ((unsigned)h < (unsigned)S && (unsigned)w < (unsigned)S)
          g = (const void*)(cbase + (size_t)(h * S + w) * 256 + cig * 8);
      }
      gl_lds16(g, (void*)&xl[buf][slot]);
    }
  };

  auto stageW = [&](int c) {
    #pragma unroll
    for (int i = 0; i < WI; ++i) {
      int slot = i * NT + tid;
      const void* g = (const void*)zpage;
      if (slot < WSLOT) {
        int fb = slot >> 6;                      // 0..35
        int tap = fb >> 2, f = fb & 3;
        int ll = slot & 63;
        g = (const void*)(wqr +
            ((((size_t)tap * 16 + blockIdx.y * 4 + f) * 8 + c) << 9) + ll * 8);
      }
      gl_lds16(g, (void*)&wl[slot]);
    }
  };

  auto compute = [&](const half8* xb) {
    #pragma unroll
    for (int tap = 0; tap < 9; ++tap) {
      const int dh = tap / 3 - 1;
      const int dw = tap - (tap / 3) * 3 - 1;
      half8 af[4];
      #pragma unroll
      for (int f = 0; f < 4; ++f)
        af[f] = wl[(tap * 4 + f) * 64 + lane];
      half8 bf[4];
      #pragma unroll
      for (int g = 0; g < 4; ++g) {
        int xp = (rg[g] + 1 + dh) * LW + (cg[g] + 1 + dw);
        bf[g] = xb[xp * 4 + (kg ^ ((xp >> 1) & 3))];
      }
      #pragma unroll
      for (int f = 0; f < 4; ++f)
        #pragma unroll
        for (int g = 0; g < 4; ++g)
          acc[f][g] = __builtin_amdgcn_mfma_f32_16x16x32_f16(af[f], bf[g], acc[f][g], 0, 0, 0);
    }
  };

  // prologue: stage chunk 0 (X and W), full drain, align
  stageX(0, 0);
  stageW(0);
  wait_vm<0>();
  __builtin_amdgcn_sched_barrier(0);
  __builtin_amdgcn_s_barrier();
  __builtin_amdgcn_sched_barrier(0);

  for (int c = 0; c < nc; ++c) {
    if (c + 1 < nc) stageX((c + 1) & 1, c + 1);
    if (c > 0) {
      if (c + 1 < nc) wait_vm<XI>();   // X(c),W(c) retired; X(c+1) in flight
      else wait_vm<0>();
      __builtin_amdgcn_sched_barrier(0);
      __builtin_amdgcn_s_barrier();
      __builtin_amdgcn_sched_barrier(0);
    }
    compute(&xl[c & 1][0]);
    __builtin_amdgcn_sched_barrier(0);
    __builtin_amdgcn_s_barrier();
    __builtin_amdgcn_sched_barrier(0);
    if (c + 1 < nc) stageW(c + 1);
  }

  // ---- epilogue: combine + write + fused BN partials ----
  const float a0 = alpha[t * 5 + 0];
  const float a1 = alpha[t * 5 + 2];
  const float a2 = alpha[t * 5 + 3];
  const float a3 = alpha[t * 5 + 4];
  float cs[4][4], cq[4][4];
  #pragma unroll
  for (int f = 0; f < 4; ++f)
    #pragma unroll
    for (int r = 0; r < 4; ++r) { cs[f][r] = 0.f; cq[f][r] = 0.f; }

  const size_t pixbase = (size_t)n * S * S + (size_t)rb * (R * S);
  #pragma unroll
  for (int f = 0; f < 4; ++f) {
    const int co = cob + f * 16 + kg * 4;
    #pragma unroll
    for (int g = 0; g < 4; ++g) {
      int lp = wn * 64 + g * 16 + l16;
      size_t idx = (pixbase + lp) * 256 + co;
      half4v v3 = *(const half4v*)(h3 + idx);
      half4v v1 = {}, v2 = {};
      if (h1) v1 = *(const half4v*)(h1 + idx);
      if (h2) v2 = *(const half4v*)(h2 + idx);
      half4v o;
      #pragma unroll
      for (int r = 0; r < 4; ++r) {
        float pv = a0 * fmaxf(acc[f][g][r], 0.f) + a3 * (float)v3[r];
        if (h1) pv += a1 * (float)v1[r];
        if (h2) pv += a2 * (float)v2[r];
        o[r] = (_Float16)pv;
        cs[f][r] += pv;
        cq[f][r] += pv * pv;
      }
      *(half4v*)(pre + idx) = o;  // pre may alias h1: same-thread RaW, safe
    }
  }

  // per-wave 64-channel partials into wl space (free after final barrier)
  float* sred = reinterpret_cast<float*>(&wl[0]);  // 512 ss + 512 sq floats
  #pragma unroll
  for (int f = 0; f < 4; ++f)
    #pragma unroll
    for (int r = 0; r < 4; ++r) {
      float a = cs[f][r], b = cq[f][r];
      #pragma unroll
      for (int m = 1; m < 16; m <<= 1) {
        a += __shfl_xor(a, m);
        b += __shfl_xor(b, m);
      }
      if (l16 == 0) {
        sred[wn * 64 + f * 16 + kg * 4 + r] = a;
        sred[512 + wn * 64 + f * 16 + kg * 4 + r] = b;
      }
    }
  __syncthreads();
  if (tid < 64) {
    float a = 0.f, b = 0.f;
    #pragma unroll
    for (int w = 0; w < 8; ++w) {
      a += sred[w * 64 + tid];
      b += sred[512 + w * 64 + tid];
    }
    psum[(size_t)blockIdx.x * 256 + cob + tid] = a;
    psum2[(size_t)blockIdx.x * 256 + cob + tid] = b;
  }
}

// ---------------- round-3 kernel for S=32/16/8 -------------------------------
template <int S, int R>
__global__ __launch_bounds__(512, 2) void conv_mfma_sm(
    const _Float16* __restrict__ in, const _Float16* __restrict__ wqr,
    const float* __restrict__ alpha, int t,
    const _Float16* h1, const _Float16* __restrict__ h2,
    const _Float16* __restrict__ h3, _Float16* pre,
    const _Float16* __restrict__ zpage,
    float* __restrict__ psum, float* __restrict__ psum2) {
  constexpr int LW = S + 2;
  constexpr int PIX = (R + 2) * LW;
  constexpr int XS = PIX * 4;
  constexpr int XS_PAD = ((XS + 63) / 64) * 64;
  constexpr int WS = 36 * 64;
  constexpr int PIXB = R * S;
  constexpr int G = PIXB / 64;

  __shared__ half8 xl[2][XS_PAD];
  __shared__ half8 wl[2][WS];
  __shared__ float sred[8][4][2][4];
  __shared__ float sredq[8][4][2][4];

  const int tid = threadIdx.x;
  const int lane = tid & 63;
  const int wid = tid >> 6;
  const int l16 = lane & 15;
  const int kg = lane >> 4;
  const int wm = wid >> 2;
  const int wn = wid & 3;

  constexpr int BPI = S / R;
  const int n = blockIdx.x / BPI;
  const int rb = blockIdx.x % BPI;
  const int cob = blockIdx.y * 64;

  const _Float16* img = in + (size_t)n * S * S * 256;

  floatx4 acc[2][G];
  #pragma unroll
  for (int f = 0; f < 2; ++f)
    #pragma unroll
    for (int g = 0; g < G; ++g)
      acc[f][g] = (floatx4){0.f, 0.f, 0.f, 0.f};

  auto stage = [&](int buf, int c) {
    const _Float16* cbase = img + c * 32;
    for (int sb = wid * 64; sb < XS_PAD; sb += 512) {
      int slot = sb + lane;
      const void* g = (const void*)zpage;
      if (slot < XS) {
        int pix = slot >> 2;
        int cig = (slot & 3) ^ ((pix >> 1) & 3);
        int hp = pix / LW, wp = pix - hp * LW;
        int h = rb * R + hp - 1, w = wp - 1;
        if ((unsigned)h < (unsigned)S && (unsigned)w < (unsigned)S)
          g = (const void*)(cbase + (size_t)(h * S + w) * 256 + cig * 8);
      }
      gl_lds16(g, (void*)&xl[buf][sb]);
    }
    for (int fb = wid; fb < 36; fb += 8) {
      int tap = fb >> 2, cogl = fb & 3;
      const _Float16* g = wqr +
          ((((size_t)tap * 16 + blockIdx.y * 4 + cogl) * 8 + c) << 9) + lane * 8;
      gl_lds16((const void*)g, (void*)&wl[buf][fb * 64]);
    }
  };

  auto compute = [&](int buf) {
    #pragma unroll
    for (int dh = -1; dh <= 1; ++dh) {
      #pragma unroll
      for (int dw = -1; dw <= 1; ++dw) {
        const int tap = (dh + 1) * 3 + (dw + 1);
        half8 af[2];
        #pragma unroll
        for (int f = 0; f < 2; ++f)
          af[f] = wl[buf][(tap * 4 + wm * 2 + f) * 64 + lane];
        half8 bf[G];
        #pragma unroll
        for (int g = 0; g < G; ++g) {
          int p = wn * (PIXB / 4) + g * 16 + l16;
          int r = p / S, cc = p - r * S;
          int lp = (r + 1 + dh) * LW + (cc + 1 + dw);
          bf[g] = xl[buf][lp * 4 + (kg ^ ((lp >> 1) & 3))];
        }
        #pragma unroll
        for (int f = 0; f < 2; ++f)
          #pragma unroll
          for (int g = 0; g < G; ++g)
            acc[f][g] = __builtin_amdgcn_mfma_f32_16x16x32_f16(af[f], bf[g], acc[f][g], 0, 0, 0);
      }
    }
  };

  stage(0, 0);
  __syncthreads();
  for (int c = 0; c < 8; ++c) {
    if (c < 7) stage((c + 1) & 1, c + 1);
    compute(c & 1);
    __syncthreads();
  }

  const float a0 = alpha[t * 5 + 0];
  const float a1 = alpha[t * 5 + 2];
  const float a2 = alpha[t * 5 + 3];
  const float a3 = alpha[t * 5 + 4];
  float ss[2][4], sq[2][4];
  #pragma unroll
  for (int f = 0; f < 2; ++f)
    #pragma unroll
    for (int r = 0; r < 4; ++r) { ss[f][r] = 0.f; sq[f][r] = 0.f; }

  const size_t pix0 = (size_t)n * S * S + (size_t)rb * PIXB;
  #pragma unroll
  for (int f = 0; f < 2; ++f) {
    const int co = cob + wm * 32 + f * 16 + kg * 4;
    #pragma unroll
    for (int g = 0; g < G; ++g) {
      int p = wn * (PIXB / 4) + g * 16 + l16;
      size_t idx = (pix0 + p) * 256 + co;
      half4v v3 = *(const half4v*)(h3 + idx);
      half4v v1 = {}, v2 = {};
      if (h1) v1 = *(const half4v*)(h1 + idx);
      if (h2) v2 = *(const half4v*)(h2 + idx);
      half4v o;
      #pragma unroll
      for (int r = 0; r < 4; ++r) {
        float pv = a0 * fmaxf(acc[f][g][r], 0.f) + a3 * (float)v3[r];
        if (h1) pv += a1 * (float)v1[r];
        if (h2) pv += a2 * (float)v2[r];
        o[r] = (_Float16)pv;
        ss[f][r] += pv;
        sq[f][r] += pv * pv;
      }
      *(half4v*)(pre + idx) = o;
    }
  }

  #pragma unroll
  for (int f = 0; f < 2; ++f)
    #pragma unroll
    for (int r = 0; r < 4; ++r) {
      float a = ss[f][r], b = sq[f][r];
      #pragma unroll
      for (int m = 1; m < 16; m <<= 1) {
        a += __shfl_xor(a, m);
        b += __shfl_xor(b, m);
      }
      if (l16 == 0) { sred[wid][kg][f][r] = a; sredq[wid][kg][f][r] = b; }
    }
  __syncthreads();
  if (tid < 64) {
    int ch = tid;
    int wmm = ch >> 5, ff = (ch >> 4) & 1, kk = (ch >> 2) & 3, rr = ch & 3;
    float a = 0.f, b = 0.f;
    #pragma unroll
    for (int w = 0; w < 4; ++w) {
      a += sred[wmm * 4 + w][kk][ff][rr];
      b += sredq[wmm * 4 + w][kk][ff][rr];
    }
    psum[(size_t)blockIdx.x * 256 + cob + ch] = a;
    psum2[(size_t)blockIdx.x * 256 + cob + ch] = b;
  }
}

// ---------------- BN stats final (256 blocks x 1 wave) ------------------------
__global__ void stats_final_kernel(const float* __restrict__ psum, const float* __restrict__ psum2,
                                   const float* __restrict__ gamma, const float* __restrict__ beta,
                                   int t, float M, int nblk,
                                   float* __restrict__ scale, float* __restrict__ shift) {
  int c = blockIdx.x;
  float s = 0.f, s2 = 0.f;
  for (int b = threadIdx.x; b < nblk; b += 64) {
    s += psum[(size_t)b * 256 + c];
    s2 += psum2[(size_t)b * 256 + c];
  }
  #pragma unroll
  for (int o = 32; o > 0; o >>= 1) {
    s += __shfl_down(s, o);
    s2 += __shfl_down(s2, o);
  }
  if (threadIdx.x == 0) {
    float mean = s / M;
    float var = s2 / M - mean * mean;  // biased, matches jnp.var
    float sc = gamma[t * 256 + c] * rsqrtf(var + 1e-5f);
    scale[c] = sc;
    shift[c] = beta[t * 256 + c] - mean * sc;
  }
}

// ---------------- BN apply (in place, grid-stride, non-pool iters) ------------
__global__ __launch_bounds__(256) void apply_kernel(
    _Float16* __restrict__ x, const float* __restrict__ scale,
    const float* __restrict__ shift, int n8) {
  for (int i = blockIdx.x * 256 + threadIdx.x; i < n8; i += gridDim.x * 256) {
    half8 v = *(half8*)(x + (size_t)i * 8);
    int c0 = (i * 8) & 255;
    half8 o;
    #pragma unroll
    for (int j = 0; j < 8; ++j) o[j] = (_Float16)((float)v[j] * scale[c0 + j] + shift[c0 + j]);
    *(half8*)(x + (size_t)i * 8) = o;
  }
}

// ---------------- fused pool (3 tensors) + BN-apply on tensor z==2 ------------
__global__ void pool3_kernel(const _Float16* __restrict__ s0, const _Float16* __restrict__ s1,
                             const _Float16* __restrict__ s2,
                             _Float16* __restrict__ d0, _Float16* __restrict__ d1,
                             _Float16* __restrict__ d2,
                             const float* __restrict__ scale, const float* __restrict__ shift,
                             int So, int total8) {
  int i = blockIdx.x * 256 + threadIdx.x;
  if (i >= total8) return;
  int z = blockIdx.y;
  const _Float16* in = (z == 0) ? s0 : (z == 1) ? s1 : s2;
  _Float16* out = (z == 0) ? d0 : (z == 1) ? d1 : d2;
  int c0 = (i & 31) * 8;
  int pix = i >> 5;
  int wo = pix % So;
  int t1 = pix / So;
  int ho = t1 % So;
  int n = t1 / So;
  int Si = So * 2;
  size_t b00 = ((size_t)(n * Si * Si) + (2 * ho) * Si + 2 * wo) * 256 + c0;
  half8 v00 = *(const half8*)(in + b00);
  half8 v01 = *(const half8*)(in + b00 + 256);
  half8 v10 = *(const half8*)(in + b00 + (size_t)Si * 256);
  half8 v11 = *(const half8*)(in + b00 + (size_t)Si * 256 + 256);
  half8 o;
  if (z == 2) {
    #pragma unroll
    for (int j = 0; j < 8; ++j) {
      float sc = scale[c0 + j], sh = shift[c0 + j];
      float a = (float)v00[j] * sc + sh;
      float b = (float)v01[j] * sc + sh;
      float c = (float)v10[j] * sc + sh;
      float d = (float)v11[j] * sc + sh;
      o[j] = (_Float16)fmaxf(fmaxf(a, b), fmaxf(c, d));
    }
  } else {
    #pragma unroll
    for (int j = 0; j < 8; ++j) {
      float m = fmaxf(fmaxf((float)v00[j], (float)v01[j]),
                      fmaxf((float)v10[j], (float)v11[j]));
      o[j] = (_Float16)m;
    }
  }
  *(half8*)(out + (size_t)pix * 256 + c0) = o;
}

// ---------------- fused head: spatial max (S=4) + linear ----------------------
__global__ __launch_bounds__(256) void head_kernel(
    const _Float16* __restrict__ x, const float* __restrict__ W,
    const float* __restrict__ b, float* __restrict__ out) {
  __shared__ float v[256];
  int n = blockIdx.x, c = threadIdx.x;
  float m = -1e30f;
  for (int p = 0; p < 16; ++p)
    m = fmaxf(m, (float)x[((size_t)(n * 16 + p)) * 256 + c]);
  v[c] = m;
  __syncthreads();
  if (c < 100) {
    float s = b[c];
    const float* w = W + c * 256;
    for (int k = 0; k < 256; ++k) s += v[k] * w[k];
    out[n * 100 + c] = s;
  }
}

// -------------------------------------------------------------------------------
extern "C" void kernel_launch(void* const* d_in, const int* in_sizes, int n_in,
                              void* d_out, int out_size, void* d_ws, size_t ws_size,
                              hipStream_t stream) {
  const float* x        = (const float*)d_in[0];
  const float* conv_w   = (const float*)d_in[1];
  const float* alpha    = (const float*)d_in[2];
  const float* bn_gamma = (const float*)d_in[3];
  const float* bn_beta  = (const float*)d_in[4];
  const float* out_w    = (const float*)d_in[5];
  const float* out_b    = (const float*)d_in[6];
  float* out = (float*)d_out;

  char* ws = (char*)d_ws;
  size_t off = 0;
  auto alloc = [&](size_t bytes) -> void* {
    void* p = (void*)(ws + off);
    off = (off + bytes + 255) & ~(size_t)255;
    return p;
  };
  const size_t SLAB = (size_t)NB * 4096 * 256 * 2;  // 32 MiB
  char* slab[4];
  size_t slabsz[4];
  for (int i = 0; i < 3; ++i) { slab[i] = (char*)alloc(SLAB); slabsz[i] = SLAB; }
  slab[3] = (char*)alloc(3 * (SLAB / 4)); slabsz[3] = 3 * (SLAB / 4);  // 24 MiB
  _Float16* wqr  = (_Float16*)alloc((size_t)9 * 256 * 256 * 2);
  float* wpart = (float*)alloc(256 * 4);
  float* psum  = (float*)alloc(256 * 256 * 4);
  float* psum2 = (float*)alloc(256 * 256 * 4);
  float* scale = (float*)alloc(256 * 4);
  float* shift = (float*)alloc(256 * 4);
  _Float16* zpage = (_Float16*)alloc(256);
  (void)ws_size;  // ~123 MiB

  const int NW = 256 * 256 * 9;

  hipMemsetAsync(zpage, 0, 256, stream);

  hipLaunchKernelGGL(wmax_part_kernel, dim3(256), dim3(256), 0, stream, conv_w, wpart, NW);
  hipLaunchKernelGGL(quant_kernel, dim3((NW + 255) / 256), dim3(256), 0, stream,
                     conv_w, wpart, wqr, NW);

  hipLaunchKernelGGL(pad_kernel, dim3((NB * 4096 * 256) / 256), dim3(256), 0, stream,
                     x, (_Float16*)slab[0]);

  auto contains = [&](int k, char* p) -> bool {
    return p && p >= slab[k] && p < slab[k] + slabsz[k];
  };

  char *p1 = nullptr, *p2 = nullptr, *p3 = slab[0];
  int S = 64;
  for (int t = 0; t < NIT; ++t) {
    char* dst;
    if (p1) {
      dst = p1;  // overwrite dying hist[1] in place
    } else {
      dst = nullptr;
      for (int k = 0; k < 3; ++k)
        if (!contains(k, p2) && !contains(k, p3)) { dst = slab[k]; break; }
    }
    const _Float16* h1 = (const _Float16*)p1;
    const _Float16* h2 = (const _Float16*)p2;
    const _Float16* h3 = (const _Float16*)p3;
    _Float16* pre = (_Float16*)dst;

    int nblk;
    switch (S) {
      case 64: {  // 64co x 512pix, 8 waves, counted-vmcnt pipeline
        int nc = (t == 0) ? 1 : 8;  // t=0: channels 3..255 exactly zero
        dim3 grid(NB * 8, 4);  nblk = NB * 8;
        hipLaunchKernelGGL((conv_mfma_v7<64, 8>), grid, dim3(512), 0, stream,
                           h3, wqr, alpha, t, nc, h1, h2, h3, pre, zpage, psum, psum2);
        break;
      }
      case 32: {  // 256 blocks = full GPU
        dim3 grid(NB * 4, 4);  nblk = NB * 4;
        hipLaunchKernelGGL((conv_mfma_sm<32, 8>), grid, dim3(512), 0, stream,
                           h3, wqr, alpha, t, h1, h2, h3, pre, zpage, psum, psum2);
        break;
      }
      case 16: {
        dim3 grid(NB * 4, 4);  nblk = NB * 4;
        hipLaunchKernelGGL((conv_mfma_sm<16, 4>), grid, dim3(512), 0, stream,
                           h3, wqr, alpha, t, h1, h2, h3, pre, zpage, psum, psum2);
        break;
      }
      default: {
        dim3 grid(NB * 1, 4);  nblk = NB * 1;
        hipLaunchKernelGGL((conv_mfma_sm<8, 8>), grid, dim3(512), 0, stream,
                           h3, wqr, alpha, t, h1, h2, h3, pre, zpage, psum, psum2);
        break;
      }
    }

    int npix = NB * S * S;
    hipLaunchKernelGGL(stats_final_kernel, dim3(256), dim3(64), 0, stream,
                       psum, psum2, bn_gamma, bn_beta, t, (float)npix, nblk, scale, shift);

    if (t % 5 != 4) {
      int n8 = npix * 32;
      int blocks = (n8 + 255) / 256;
      if (blocks > 2048) blocks = 2048;
      hipLaunchKernelGGL(apply_kernel, dim3(blocks), dim3(256), 0, stream,
                         pre, scale, shift, n8);
      p1 = p2; p2 = p3; p3 = dst;
    } else {
      char* q1 = p2;
      char* q2 = p3;
      char* q3 = dst;
      int So = S / 2;
      size_t qbytes = (size_t)NB * So * So * 256 * 2;
      char* fs = nullptr;
      for (int k = 0; k < 4; ++k)
        if (!contains(k, q1) && !contains(k, q2) && !contains(k, q3)) { fs = slab[k]; break; }
      int total8 = NB * So * So * 32;
      dim3 pg((total8 + 255) / 256, 3);
      hipLaunchKernelGGL(pool3_kernel, pg, dim3(256), 0, stream,
                         (const _Float16*)q1, (const _Float16*)q2, (const _Float16*)q3,
                         (_Float16*)fs, (_Float16*)(fs + qbytes), (_Float16*)(fs + 2 * qbytes),
                         scale, shift, So, total8);
      p1 = fs; p2 = fs + qbytes; p3 = fs + 2 * qbytes;
      S = So;
    }
  }

  hipLaunchKernelGGL(head_kernel, dim3(16), dim3(256), 0, stream,
                     (const _Float16*)p3, out_w, out_b, out);
}